// Round 3
// baseline (1110.191 us; speedup 1.0000x reference)
//
#include <hip/hip_runtime.h>
#include <hip/hip_bf16.h>

#define N_NODES 50000
#define N_EDGES 800000
#define F_IN    128
#define F_HID   128
#define F_OUT   40

// ---- 0. index-width sniff: int64 edge data has zero high words
__global__ void k_sniff(const unsigned int* __restrict__ w, int* __restrict__ flag) {
    __shared__ int nz;
    if (threadIdx.x == 0) nz = 0;
    __syncthreads();
    int local = 0;
    for (int i = threadIdx.x; i < 4096; i += 256)
        if (w[2 * i + 1] != 0u) local = 1;
    if (local) atomicOr(&nz, 1);
    __syncthreads();
    if (threadIdx.x == 0) flag[0] = (nz == 0) ? 1 : 0;   // 1 => int64 layout
}

__device__ __forceinline__ int ld_src(const unsigned int* w, int is64, int e) {
    return is64 ? (int)w[2 * e] : (int)w[e];
}
__device__ __forceinline__ int ld_dst(const unsigned int* w, int is64, int e) {
    return is64 ? (int)w[2 * (N_EDGES + e)] : (int)w[N_EDGES + e];
}

// ---- 1. degree (count of incoming edges), fp32 atomics (exact for counts < 2^24)
__global__ void k_deg(const unsigned int* __restrict__ w, const int* __restrict__ flag,
                      float* __restrict__ deg) {
    int e = blockIdx.x * blockDim.x + threadIdx.x;
    if (e < N_EDGES) atomicAdd(&deg[ld_dst(w, flag[0], e)], 1.0f);
}

// ---- 2. dinv = rsqrt(deg + 1) in place
__global__ void k_dinv(float* __restrict__ deg) {
    int i = blockIdx.x * blockDim.x + threadIdx.x;
    if (i < N_NODES) deg[i] = rsqrtf(deg[i] + 1.0f);
}

// ---- 3. h1 = x @ W1   (50000x128 @ 128x128), 2 nodes per 256-thread block
__global__ void k_gemm1(const float* __restrict__ x,
                        const float* __restrict__ W,
                        float* __restrict__ h1) {
    __shared__ float xs[2][F_IN];
    int r = threadIdx.x >> 7;        // node within block
    int j = threadIdx.x & 127;       // output column
    int node = blockIdx.x * 2 + r;
    xs[r][j] = x[node * F_IN + j];
    __syncthreads();
    float acc = 0.f;
#pragma unroll 8
    for (int k = 0; k < F_IN; k++)
        acc += xs[r][k] * W[k * F_HID + j];
    h1[node * F_HID + j] = acc;
}

// ---- 4. agg1[dst] += h1[src] * norm — one wave per edge, float2 per lane
__global__ void k_agg1(const unsigned int* __restrict__ w, const int* __restrict__ flag,
                       const float* __restrict__ dinv,
                       const float* __restrict__ h1, float* __restrict__ agg) {
    int wave = threadIdx.x >> 6;
    int lane = threadIdx.x & 63;
    int e = blockIdx.x * 4 + wave;
    if (e >= N_EDGES) return;
    int is64 = flag[0];
    int s = ld_src(w, is64, e), d = ld_dst(w, is64, e);
    float norm = dinv[s] * dinv[d];
    float2 v = ((const float2*)(h1 + s * F_HID))[lane];
    float* ap = agg + d * F_HID + lane * 2;
    atomicAdd(ap,     v.x * norm);
    atomicAdd(ap + 1, v.y * norm);
}

// ---- 5. h1r = relu(agg1 + h1*dinv^2 + b1), in place into agg1
__global__ void k_post1(const float* __restrict__ h1, const float* __restrict__ dinv,
                        const float* __restrict__ b1, float* __restrict__ agg) {
    int idx = blockIdx.x * blockDim.x + threadIdx.x;
    int i = idx >> 7, f = idx & 127;
    float di = dinv[i];
    float v = agg[idx] + h1[idx] * di * di + b1[f];
    agg[idx] = fmaxf(v, 0.f);
}

// ---- 6. h2 = h1r @ W2  (50000x128 @ 128x40), 4 nodes per 256-thread block
__global__ void k_gemm2(const float* __restrict__ h1r,
                        const float* __restrict__ W2,
                        float* __restrict__ h2) {
    __shared__ float xs[4][F_HID];
    int wave = threadIdx.x >> 6, lane = threadIdx.x & 63;
    int node = blockIdx.x * 4 + wave;
    xs[wave][lane]      = h1r[node * F_HID + lane];
    xs[wave][lane + 64] = h1r[node * F_HID + lane + 64];
    __syncthreads();
    if (lane < F_OUT) {
        float acc = 0.f;
#pragma unroll 8
        for (int k = 0; k < F_HID; k++)
            acc += xs[wave][k] * W2[k * F_OUT + lane];
        h2[node * F_OUT + lane] = acc;
    }
}

// ---- 7. agg2[dst] += h2[src] * norm — one wave per edge, lanes 0..39
__global__ void k_agg2(const unsigned int* __restrict__ w, const int* __restrict__ flag,
                       const float* __restrict__ dinv,
                       const float* __restrict__ h2, float* __restrict__ agg) {
    int wave = threadIdx.x >> 6;
    int lane = threadIdx.x & 63;
    int e = blockIdx.x * 4 + wave;
    if (e >= N_EDGES) return;
    int is64 = flag[0];
    int s = ld_src(w, is64, e), d = ld_dst(w, is64, e);
    if (lane >= F_OUT) return;
    float norm = dinv[s] * dinv[d];
    atomicAdd(&agg[d * F_OUT + lane], h2[s * F_OUT + lane] * norm);
}

// ---- 8. out = log_softmax(agg2 + h2*dinv^2 + b2), one wave per node, FP32 out
__global__ void k_post2(const float* __restrict__ h2, const float* __restrict__ agg,
                        const float* __restrict__ dinv, const float* __restrict__ b2,
                        float* __restrict__ out) {
    int wave = threadIdx.x >> 6, lane = threadIdx.x & 63;
    int node = blockIdx.x * 4 + wave;
    float di = dinv[node];
    float v = -INFINITY;
    if (lane < F_OUT)
        v = agg[node * F_OUT + lane] + h2[node * F_OUT + lane] * di * di + b2[lane];
    float m = v;
    for (int off = 32; off; off >>= 1) m = fmaxf(m, __shfl_xor(m, off));
    float ex = (lane < F_OUT) ? expf(v - m) : 0.f;
    float ssum = ex;
    for (int off = 32; off; off >>= 1) ssum += __shfl_xor(ssum, off);
    float ls = logf(ssum);
    if (lane < F_OUT)
        out[node * F_OUT + lane] = v - m - ls;
}

extern "C" void kernel_launch(void* const* d_in, const int* in_sizes, int n_in,
                              void* d_out, int out_size, void* d_ws, size_t ws_size,
                              hipStream_t stream) {
    const float* x  = (const float*)d_in[0];
    const float* W1 = (const float*)d_in[1];
    const float* b1 = (const float*)d_in[2];
    const float* W2 = (const float*)d_in[3];
    const float* b2 = (const float*)d_in[4];
    const unsigned int* ew = (const unsigned int*)d_in[5];  // edge words (int32 or int64)
    float* out = (float*)d_out;                             // fp32 output, [50000,40]

    // workspace layout (~51.4 MB total):
    char* ws = (char*)d_ws;
    int*   flag = (int*)ws;   ws += 256;
    float* dinv = (float*)ws; ws += ((N_NODES * 4 + 255) / 256) * 256;
    float* agg1 = (float*)ws; ws += (size_t)N_NODES * F_HID * 4;   // becomes h1r
    float* h1   = (float*)ws;                                      // 25.6 MB region
    float* h2   = h1;                                              // reused after post1
    float* agg2 = h1 + (size_t)N_NODES * F_OUT;                    // h1 region + 8 MB

    k_sniff<<<1, 256, 0, stream>>>(ew, flag);
    hipMemsetAsync(dinv, 0, (size_t)N_NODES * 4, stream);
    hipMemsetAsync(agg1, 0, (size_t)N_NODES * F_HID * 4, stream);

    k_deg  <<<(N_EDGES + 255) / 256, 256, 0, stream>>>(ew, flag, dinv);
    k_dinv <<<(N_NODES + 255) / 256, 256, 0, stream>>>(dinv);
    k_gemm1<<<N_NODES / 2, 256, 0, stream>>>(x, W1, h1);
    k_agg1 <<<N_EDGES / 4, 256, 0, stream>>>(ew, flag, dinv, h1, agg1);
    k_post1<<<(N_NODES * F_HID) / 256, 256, 0, stream>>>(h1, dinv, b1, agg1);
    // h1 buffer now dead -> reuse for h2 (first 8 MB) and agg2 (next 8 MB)
    hipMemsetAsync(agg2, 0, (size_t)N_NODES * F_OUT * 4, stream);
    k_gemm2<<<N_NODES / 4, 256, 0, stream>>>(agg1, W2, h2);
    k_agg2 <<<N_EDGES / 4, 256, 0, stream>>>(ew, flag, dinv, h2, agg2);
    k_post2<<<N_NODES / 4, 256, 0, stream>>>(h2, agg2, dinv, b2, out);
}

// Round 4
// 485.092 us; speedup vs baseline: 2.2886x; 2.2886x over previous
//
#include <hip/hip_runtime.h>
#include <hip/hip_bf16.h>

#define N_NODES 50000
#define N_EDGES 800000
#define F_IN    128
#define F_HID   128
#define F_OUT   40
#define SCAN_BLOCKS ((N_NODES + 255) / 256)   // 196

// ---- 0. index-width sniff: int64 edge data has zero high words
__global__ void k_sniff(const unsigned int* __restrict__ w, int* __restrict__ flag) {
    __shared__ int nz;
    if (threadIdx.x == 0) nz = 0;
    __syncthreads();
    int local = 0;
    for (int i = threadIdx.x; i < 4096; i += 256)
        if (w[2 * i + 1] != 0u) local = 1;
    if (local) atomicOr(&nz, 1);
    __syncthreads();
    if (threadIdx.x == 0) flag[0] = (nz == 0) ? 1 : 0;   // 1 => int64 layout
}

__device__ __forceinline__ int ld_src(const unsigned int* w, int is64, int e) {
    return is64 ? (int)w[2 * e] : (int)w[e];
}
__device__ __forceinline__ int ld_dst(const unsigned int* w, int is64, int e) {
    return is64 ? (int)w[2 * (N_EDGES + e)] : (int)w[N_EDGES + e];
}

// ---- 1. histogram of dst (int atomics)
__global__ void k_hist(const unsigned int* __restrict__ w, const int* __restrict__ flag,
                       int* __restrict__ deg) {
    int e = blockIdx.x * blockDim.x + threadIdx.x;
    if (e < N_EDGES) atomicAdd(&deg[ld_dst(w, flag[0], e)], 1);
}

// ---- 2a. per-block exclusive scan of deg -> rowptr (partial), block sums
__global__ void k_scan1(const int* __restrict__ deg, int* __restrict__ rowptr,
                        int* __restrict__ bsum) {
    __shared__ int sh[256];
    int tid = threadIdx.x;
    int i = blockIdx.x * 256 + tid;
    int v = (i < N_NODES) ? deg[i] : 0;
    sh[tid] = v;
    __syncthreads();
    for (int off = 1; off < 256; off <<= 1) {
        int t = (tid >= off) ? sh[tid - off] : 0;
        __syncthreads();
        sh[tid] += t;
        __syncthreads();
    }
    if (i < N_NODES) rowptr[i] = sh[tid] - v;      // exclusive within block
    if (tid == 255) bsum[blockIdx.x] = sh[255];
}

// ---- 2b. scan the block sums (single block; SCAN_BLOCKS <= 256)
__global__ void k_scan2(int* __restrict__ bsum, int* __restrict__ boff) {
    __shared__ int sh[256];
    int tid = threadIdx.x;
    int v = (tid < SCAN_BLOCKS) ? bsum[tid] : 0;
    sh[tid] = v;
    __syncthreads();
    for (int off = 1; off < 256; off <<= 1) {
        int t = (tid >= off) ? sh[tid - off] : 0;
        __syncthreads();
        sh[tid] += t;
        __syncthreads();
    }
    if (tid < SCAN_BLOCKS) boff[tid] = sh[tid] - v;
}

// ---- 2c. finalize rowptr, init pos, compute dinv.  NOTE: pos aliases deg.
__global__ void k_scan3(const int* __restrict__ deg, const int* __restrict__ boff,
                        int* __restrict__ rowptr, int* __restrict__ pos,
                        float* __restrict__ dinv) {
    int i = blockIdx.x * 256 + threadIdx.x;
    if (i >= N_NODES) return;
    int dg = deg[i];                       // read BEFORE pos write (aliased)
    int rp = rowptr[i] + boff[blockIdx.x];
    rowptr[i] = rp;
    pos[i] = rp;
    dinv[i] = rsqrtf((float)dg + 1.0f);
    if (i == 0) rowptr[N_NODES] = N_EDGES;
}

// ---- 3. scatter src into dst-sorted order
__global__ void k_scatter(const unsigned int* __restrict__ w, const int* __restrict__ flag,
                          int* __restrict__ pos, int* __restrict__ src_sorted) {
    int e = blockIdx.x * blockDim.x + threadIdx.x;
    if (e >= N_EDGES) return;
    int is64 = flag[0];
    int s = ld_src(w, is64, e), d = ld_dst(w, is64, e);
    int slot = atomicAdd(&pos[d], 1);
    src_sorted[slot] = s;
}

// ---- 4. h1 = x @ W1   (50000x128 @ 128x128), 2 nodes per 256-thread block
__global__ void k_gemm1(const float* __restrict__ x,
                        const float* __restrict__ W,
                        float* __restrict__ h1) {
    __shared__ float xs[2][F_IN];
    int r = threadIdx.x >> 7;
    int j = threadIdx.x & 127;
    int node = blockIdx.x * 2 + r;
    xs[r][j] = x[node * F_IN + j];
    __syncthreads();
    float acc = 0.f;
#pragma unroll 8
    for (int k = 0; k < F_IN; k++)
        acc += xs[r][k] * W[k * F_HID + j];
    h1[node * F_HID + j] = acc;
}

// ---- 5. fused layer-1 aggregate + self-loop + bias + relu. One wave per node.
__global__ void k_agg1f(const int* __restrict__ rowptr, const int* __restrict__ srcs,
                        const float* __restrict__ dinv, const float* __restrict__ h1,
                        const float* __restrict__ b1, float* __restrict__ h1r) {
    int wave = threadIdx.x >> 6, lane = threadIdx.x & 63;
    int node = blockIdx.x * 4 + wave;
    float di = dinv[node];
    int beg = rowptr[node], end = rowptr[node + 1];
    float2 acc = ((const float2*)(h1 + (size_t)node * F_HID))[lane];
    float w0 = di * di;
    acc.x *= w0; acc.y *= w0;
    for (int e = beg; e < end; e++) {
        int s = srcs[e];
        float w = dinv[s] * di;
        float2 v = ((const float2*)(h1 + (size_t)s * F_HID))[lane];
        acc.x += v.x * w;
        acc.y += v.y * w;
    }
    float2 bb = ((const float2*)b1)[lane];
    acc.x = fmaxf(acc.x + bb.x, 0.f);
    acc.y = fmaxf(acc.y + bb.y, 0.f);
    ((float2*)(h1r + (size_t)node * F_HID))[lane] = acc;
}

// ---- 6. h2 = h1r @ W2  (50000x128 @ 128x40), 4 nodes per 256-thread block
__global__ void k_gemm2(const float* __restrict__ h1r,
                        const float* __restrict__ W2,
                        float* __restrict__ h2) {
    __shared__ float xs[4][F_HID];
    int wave = threadIdx.x >> 6, lane = threadIdx.x & 63;
    int node = blockIdx.x * 4 + wave;
    xs[wave][lane]      = h1r[node * F_HID + lane];
    xs[wave][lane + 64] = h1r[node * F_HID + lane + 64];
    __syncthreads();
    if (lane < F_OUT) {
        float acc = 0.f;
#pragma unroll 8
        for (int k = 0; k < F_HID; k++)
            acc += xs[wave][k] * W2[k * F_OUT + lane];
        h2[node * F_OUT + lane] = acc;
    }
}

// ---- 7. fused layer-2 aggregate + self-loop + bias + log_softmax. One wave per node.
__global__ void k_agg2f(const int* __restrict__ rowptr, const int* __restrict__ srcs,
                        const float* __restrict__ dinv, const float* __restrict__ h2,
                        const float* __restrict__ b2, float* __restrict__ out) {
    int wave = threadIdx.x >> 6, lane = threadIdx.x & 63;
    int node = blockIdx.x * 4 + wave;
    float di = dinv[node];
    int beg = rowptr[node], end = rowptr[node + 1];
    int l = (lane < F_OUT) ? lane : 0;
    float acc = h2[(size_t)node * F_OUT + l] * di * di;
    for (int e = beg; e < end; e++) {
        int s = srcs[e];
        float w = dinv[s] * di;
        acc += h2[(size_t)s * F_OUT + l] * w;
    }
    float v = (lane < F_OUT) ? acc + b2[lane] : -INFINITY;
    float m = v;
    for (int off = 32; off; off >>= 1) m = fmaxf(m, __shfl_xor(m, off));
    float ex = (lane < F_OUT) ? __expf(v - m) : 0.f;
    float ssum = ex;
    for (int off = 32; off; off >>= 1) ssum += __shfl_xor(ssum, off);
    float ls = __logf(ssum);
    if (lane < F_OUT)
        out[(size_t)node * F_OUT + lane] = v - m - ls;
}

extern "C" void kernel_launch(void* const* d_in, const int* in_sizes, int n_in,
                              void* d_out, int out_size, void* d_ws, size_t ws_size,
                              hipStream_t stream) {
    const float* x  = (const float*)d_in[0];
    const float* W1 = (const float*)d_in[1];
    const float* b1 = (const float*)d_in[2];
    const float* W2 = (const float*)d_in[3];
    const float* b2 = (const float*)d_in[4];
    const unsigned int* ew = (const unsigned int*)d_in[5];
    float* out = (float*)d_out;

    // workspace layout (~55 MB)
    char* ws = (char*)d_ws;
    int*   flag   = (int*)ws;   ws += 256;
    int*   deg    = (int*)ws;   ws += ((N_NODES * 4 + 255) / 256) * 256;  // pos aliases deg
    int*   pos    = deg;
    float* dinv   = (float*)ws; ws += ((N_NODES * 4 + 255) / 256) * 256;
    int*   rowptr = (int*)ws;   ws += (((N_NODES + 1) * 4 + 255) / 256) * 256;
    int*   bsum   = (int*)ws;   ws += 1024;
    int*   boff   = (int*)ws;   ws += 1024;
    int*   srcs   = (int*)ws;   ws += (size_t)N_EDGES * 4;
    float* h1     = (float*)ws; ws += (size_t)N_NODES * F_HID * 4;
    float* h2     = h1;                                   // h1 dead after k_agg1f
    float* h1r    = (float*)ws; ws += (size_t)N_NODES * F_HID * 4;

    k_sniff<<<1, 256, 0, stream>>>(ew, flag);
    hipMemsetAsync(deg, 0, (size_t)N_NODES * 4, stream);
    k_hist   <<<(N_EDGES + 255) / 256, 256, 0, stream>>>(ew, flag, deg);
    k_scan1  <<<SCAN_BLOCKS, 256, 0, stream>>>(deg, rowptr, bsum);
    k_scan2  <<<1, 256, 0, stream>>>(bsum, boff);
    k_scan3  <<<SCAN_BLOCKS, 256, 0, stream>>>(deg, boff, rowptr, pos, dinv);
    k_scatter<<<(N_EDGES + 255) / 256, 256, 0, stream>>>(ew, flag, pos, srcs);
    k_gemm1  <<<N_NODES / 2, 256, 0, stream>>>(x, W1, h1);
    k_agg1f  <<<N_NODES / 4, 256, 0, stream>>>(rowptr, srcs, dinv, h1, b1, h1r);
    k_gemm2  <<<N_NODES / 4, 256, 0, stream>>>(h1r, W2, h2);
    k_agg2f  <<<N_NODES / 4, 256, 0, stream>>>(rowptr, srcs, dinv, h2, b2, out);
}

// Round 5
// 376.420 us; speedup vs baseline: 2.9493x; 1.2887x over previous
//
#include <hip/hip_runtime.h>
#include <hip/hip_bf16.h>

#define N_NODES 50000
#define N_EDGES 800000
#define F_IN    128
#define F_HID   128
#define F_OUT   40
#define SCAN_BLOCKS ((N_NODES + 255) / 256)   // 196
#define N_TILES (N_NODES / 16)                // 3125 (exact)

typedef __attribute__((ext_vector_type(8))) short bf16x8;   // 8 bf16 = 4 VGPRs
typedef __attribute__((ext_vector_type(4))) float f32x4;

__device__ __forceinline__ float2 unpack_bf2(unsigned u) {
    float2 r;
    r.x = __uint_as_float(u << 16);
    r.y = __uint_as_float(u & 0xffff0000u);
    return r;
}

// ---- 0. index-width sniff: int64 edge data has zero high words
__global__ void k_sniff(const unsigned int* __restrict__ w, int* __restrict__ flag) {
    __shared__ int nz;
    if (threadIdx.x == 0) nz = 0;
    __syncthreads();
    int local = 0;
    for (int i = threadIdx.x; i < 4096; i += 256)
        if (w[2 * i + 1] != 0u) local = 1;
    if (local) atomicOr(&nz, 1);
    __syncthreads();
    if (threadIdx.x == 0) flag[0] = (nz == 0) ? 1 : 0;
}

__device__ __forceinline__ int ld_src(const unsigned int* w, int is64, int e) {
    return is64 ? (int)w[2 * e] : (int)w[e];
}
__device__ __forceinline__ int ld_dst(const unsigned int* w, int is64, int e) {
    return is64 ? (int)w[2 * (N_EDGES + e)] : (int)w[N_EDGES + e];
}

// ---- 1. histogram of dst
__global__ void k_hist(const unsigned int* __restrict__ w, const int* __restrict__ flag,
                       int* __restrict__ deg) {
    int e = blockIdx.x * blockDim.x + threadIdx.x;
    if (e < N_EDGES) atomicAdd(&deg[ld_dst(w, flag[0], e)], 1);
}

// ---- 2a/2b/2c. exclusive scan -> rowptr, pos, dinv
__global__ void k_scan1(const int* __restrict__ deg, int* __restrict__ rowptr,
                        int* __restrict__ bsum) {
    __shared__ int sh[256];
    int tid = threadIdx.x;
    int i = blockIdx.x * 256 + tid;
    int v = (i < N_NODES) ? deg[i] : 0;
    sh[tid] = v;
    __syncthreads();
    for (int off = 1; off < 256; off <<= 1) {
        int t = (tid >= off) ? sh[tid - off] : 0;
        __syncthreads();
        sh[tid] += t;
        __syncthreads();
    }
    if (i < N_NODES) rowptr[i] = sh[tid] - v;
    if (tid == 255) bsum[blockIdx.x] = sh[255];
}
__global__ void k_scan2(int* __restrict__ bsum, int* __restrict__ boff) {
    __shared__ int sh[256];
    int tid = threadIdx.x;
    int v = (tid < SCAN_BLOCKS) ? bsum[tid] : 0;
    sh[tid] = v;
    __syncthreads();
    for (int off = 1; off < 256; off <<= 1) {
        int t = (tid >= off) ? sh[tid - off] : 0;
        __syncthreads();
        sh[tid] += t;
        __syncthreads();
    }
    if (tid < SCAN_BLOCKS) boff[tid] = sh[tid] - v;
}
__global__ void k_scan3(const int* __restrict__ deg, const int* __restrict__ boff,
                        int* __restrict__ rowptr, int* __restrict__ pos,
                        float* __restrict__ dinv) {
    int i = blockIdx.x * 256 + threadIdx.x;
    if (i >= N_NODES) return;
    int dg = deg[i];
    int rp = rowptr[i] + boff[blockIdx.x];
    rowptr[i] = rp;
    pos[i] = rp;
    dinv[i] = rsqrtf((float)dg + 1.0f);
    if (i == 0) rowptr[N_NODES] = N_EDGES;
}

// ---- 3. scatter src into dst-sorted order
__global__ void k_scatter(const unsigned int* __restrict__ w, const int* __restrict__ flag,
                          int* __restrict__ pos, int* __restrict__ src_sorted) {
    int e = blockIdx.x * blockDim.x + threadIdx.x;
    if (e >= N_EDGES) return;
    int is64 = flag[0];
    int s = ld_src(w, is64, e), d = ld_dst(w, is64, e);
    int slot = atomicAdd(&pos[d], 1);
    src_sorted[slot] = s;
}

// ---- 4a. x fp32 -> bf16 (row-major unchanged)
__global__ void k_cvt_x(const float* __restrict__ x, __hip_bfloat16* __restrict__ xb) {
    int i = (blockIdx.x * blockDim.x + threadIdx.x) * 4;
    float4 v = *(const float4*)(x + i);
    xb[i]     = __float2bfloat16(v.x);
    xb[i + 1] = __float2bfloat16(v.y);
    xb[i + 2] = __float2bfloat16(v.z);
    xb[i + 3] = __float2bfloat16(v.w);
}

// ---- 4b. W1 [128][128] -> W1T bf16 [n][k]
__global__ void k_cvt_w1t(const float* __restrict__ W1, __hip_bfloat16* __restrict__ w1t) {
    int idx = blockIdx.x * blockDim.x + threadIdx.x;   // 16384
    int n = idx >> 7, k = idx & 127;
    w1t[idx] = __float2bfloat16(W1[k * F_HID + n]);
}

// ---- 4c. W2 [128][40] -> W2T bf16 [48][128], rows 40..47 zero
__global__ void k_cvt_w2t(const float* __restrict__ W2, __hip_bfloat16* __restrict__ w2t) {
    int idx = blockIdx.x * blockDim.x + threadIdx.x;   // 48*128 = 6144
    int n = idx >> 7, k = idx & 127;
    w2t[idx] = __float2bfloat16(n < F_OUT ? W2[k * F_OUT + n] : 0.f);
}

// ---- 5. h1 = x @ W1 via MFMA. One wave per 16-node tile, full 128 cols. h1 out bf16.
__global__ void k_gemm1m(const __hip_bfloat16* __restrict__ xb,
                         const __hip_bfloat16* __restrict__ w1t,
                         __hip_bfloat16* __restrict__ h1b) {
    int wave = threadIdx.x >> 6, lane = threadIdx.x & 63;
    int tile = blockIdx.x * 4 + wave;
    if (tile >= N_TILES) return;
    int node0 = tile * 16;
    int m = lane & 15, q = lane >> 4;
    // A frags: A[m][k], lane holds k = q*8 + j (+32 per kt)
    bf16x8 A[4];
    const __hip_bfloat16* arow = xb + (size_t)(node0 + m) * F_IN + q * 8;
#pragma unroll
    for (int kt = 0; kt < 4; kt++)
        A[kt] = *(const bf16x8*)(arow + kt * 32);
#pragma unroll
    for (int c = 0; c < 8; c++) {
        f32x4 acc = {0.f, 0.f, 0.f, 0.f};
        const __hip_bfloat16* brow = w1t + (size_t)(c * 16 + m) * F_IN + q * 8;
#pragma unroll
        for (int kt = 0; kt < 4; kt++) {
            bf16x8 B = *(const bf16x8*)(brow + kt * 32);
            acc = __builtin_amdgcn_mfma_f32_16x16x32_bf16(A[kt], B, acc, 0, 0, 0);
        }
#pragma unroll
        for (int r = 0; r < 4; r++)
            h1b[(size_t)(node0 + q * 4 + r) * F_HID + c * 16 + m] = __float2bfloat16(acc[r]);
    }
}

// ---- 6. fused layer-1 aggregate + self-loop + bias + relu. One wave per node, bf16 in/out.
__global__ void k_agg1f(const int* __restrict__ rowptr, const int* __restrict__ srcs,
                        const float* __restrict__ dinv, const __hip_bfloat16* __restrict__ h1b,
                        const float* __restrict__ b1, __hip_bfloat16* __restrict__ h1rb) {
    int wave = threadIdx.x >> 6, lane = threadIdx.x & 63;
    int node = blockIdx.x * 4 + wave;
    float di = dinv[node];
    int beg = rowptr[node], end = rowptr[node + 1];
    const unsigned* h1u = (const unsigned*)h1b;
    float2 acc = unpack_bf2(h1u[(size_t)node * 64 + lane]);
    float w0 = di * di;
    acc.x *= w0; acc.y *= w0;
    for (int e = beg; e < end; e++) {
        int s = srcs[e];
        float w = dinv[s] * di;
        float2 v = unpack_bf2(h1u[(size_t)s * 64 + lane]);
        acc.x += v.x * w;
        acc.y += v.y * w;
    }
    acc.x = fmaxf(acc.x + b1[2 * lane], 0.f);
    acc.y = fmaxf(acc.y + b1[2 * lane + 1], 0.f);
    h1rb[(size_t)node * F_HID + 2 * lane]     = __float2bfloat16(acc.x);
    h1rb[(size_t)node * F_HID + 2 * lane + 1] = __float2bfloat16(acc.y);
}

// ---- 7. h2 = h1r @ W2 via MFMA (N padded 40->48). h2 out fp32.
__global__ void k_gemm2m(const __hip_bfloat16* __restrict__ h1rb,
                         const __hip_bfloat16* __restrict__ w2t,
                         float* __restrict__ h2) {
    int wave = threadIdx.x >> 6, lane = threadIdx.x & 63;
    int tile = blockIdx.x * 4 + wave;
    if (tile >= N_TILES) return;
    int node0 = tile * 16;
    int m = lane & 15, q = lane >> 4;
    bf16x8 A[4];
    const __hip_bfloat16* arow = h1rb + (size_t)(node0 + m) * F_HID + q * 8;
#pragma unroll
    for (int kt = 0; kt < 4; kt++)
        A[kt] = *(const bf16x8*)(arow + kt * 32);
#pragma unroll
    for (int c = 0; c < 3; c++) {
        f32x4 acc = {0.f, 0.f, 0.f, 0.f};
        const __hip_bfloat16* brow = w2t + (size_t)(c * 16 + m) * F_HID + q * 8;
#pragma unroll
        for (int kt = 0; kt < 4; kt++) {
            bf16x8 B = *(const bf16x8*)(brow + kt * 32);
            acc = __builtin_amdgcn_mfma_f32_16x16x32_bf16(A[kt], B, acc, 0, 0, 0);
        }
        int col = c * 16 + m;
        if (col < F_OUT) {
#pragma unroll
            for (int r = 0; r < 4; r++)
                h2[(size_t)(node0 + q * 4 + r) * F_OUT + col] = acc[r];
        }
    }
}

// ---- 8. fused layer-2 aggregate + self-loop + bias + log_softmax. One wave per node.
__global__ void k_agg2f(const int* __restrict__ rowptr, const int* __restrict__ srcs,
                        const float* __restrict__ dinv, const float* __restrict__ h2,
                        const float* __restrict__ b2, float* __restrict__ out) {
    int wave = threadIdx.x >> 6, lane = threadIdx.x & 63;
    int node = blockIdx.x * 4 + wave;
    float di = dinv[node];
    int beg = rowptr[node], end = rowptr[node + 1];
    int l = (lane < F_OUT) ? lane : 0;
    float acc = h2[(size_t)node * F_OUT + l] * di * di;
    for (int e = beg; e < end; e++) {
        int s = srcs[e];
        float w = dinv[s] * di;
        acc += h2[(size_t)s * F_OUT + l] * w;
    }
    float v = (lane < F_OUT) ? acc + b2[lane] : -INFINITY;
    float m = v;
    for (int off = 32; off; off >>= 1) m = fmaxf(m, __shfl_xor(m, off));
    float ex = (lane < F_OUT) ? __expf(v - m) : 0.f;
    float ssum = ex;
    for (int off = 32; off; off >>= 1) ssum += __shfl_xor(ssum, off);
    float ls = __logf(ssum);
    if (lane < F_OUT)
        out[(size_t)node * F_OUT + lane] = v - m - ls;
}

extern "C" void kernel_launch(void* const* d_in, const int* in_sizes, int n_in,
                              void* d_out, int out_size, void* d_ws, size_t ws_size,
                              hipStream_t stream) {
    const float* x  = (const float*)d_in[0];
    const float* W1 = (const float*)d_in[1];
    const float* b1 = (const float*)d_in[2];
    const float* W2 = (const float*)d_in[3];
    const float* b2 = (const float*)d_in[4];
    const unsigned int* ew = (const unsigned int*)d_in[5];
    float* out = (float*)d_out;

    // workspace (~50 MB)
    char* ws = (char*)d_ws;
    int*   flag   = (int*)ws;   ws += 256;
    int*   deg    = (int*)ws;   ws += ((N_NODES * 4 + 255) / 256) * 256;
    int*   pos    = deg;                                        // aliases deg
    float* dinv   = (float*)ws; ws += ((N_NODES * 4 + 255) / 256) * 256;
    int*   rowptr = (int*)ws;   ws += (((N_NODES + 1) * 4 + 255) / 256) * 256;
    int*   bsum   = (int*)ws;   ws += 1024;
    int*   boff   = (int*)ws;   ws += 1024;
    int*   srcs   = (int*)ws;   ws += (size_t)N_EDGES * 4;
    __hip_bfloat16* xb   = (__hip_bfloat16*)ws; ws += (size_t)N_NODES * F_IN * 2;
    __hip_bfloat16* w1t  = (__hip_bfloat16*)ws; ws += F_IN * F_HID * 2;
    __hip_bfloat16* w2t  = (__hip_bfloat16*)ws; ws += 48 * F_HID * 2;
    __hip_bfloat16* h1b  = (__hip_bfloat16*)ws; ws += (size_t)N_NODES * F_HID * 2;
    __hip_bfloat16* h1rb = (__hip_bfloat16*)ws; ws += (size_t)N_NODES * F_HID * 2;
    float* h2 = (float*)ws;     ws += (size_t)N_NODES * F_OUT * 4;

    k_sniff<<<1, 256, 0, stream>>>(ew, flag);
    hipMemsetAsync(deg, 0, (size_t)N_NODES * 4, stream);
    k_hist   <<<(N_EDGES + 255) / 256, 256, 0, stream>>>(ew, flag, deg);
    k_scan1  <<<SCAN_BLOCKS, 256, 0, stream>>>(deg, rowptr, bsum);
    k_scan2  <<<1, 256, 0, stream>>>(bsum, boff);
    k_scan3  <<<SCAN_BLOCKS, 256, 0, stream>>>(deg, boff, rowptr, pos, dinv);
    k_scatter<<<(N_EDGES + 255) / 256, 256, 0, stream>>>(ew, flag, pos, srcs);

    k_cvt_x  <<<(N_NODES * F_IN / 4) / 256, 256, 0, stream>>>(x, xb);
    k_cvt_w1t<<<(F_IN * F_HID) / 256, 256, 0, stream>>>(W1, w1t);
    k_cvt_w2t<<<(48 * F_HID) / 256, 256, 0, stream>>>(W2, w2t);

    k_gemm1m <<<(N_TILES + 3) / 4, 256, 0, stream>>>(xb, w1t, h1b);
    k_agg1f  <<<N_NODES / 4, 256, 0, stream>>>(rowptr, srcs, dinv, h1b, b1, h1rb);
    k_gemm2m <<<(N_TILES + 3) / 4, 256, 0, stream>>>(h1rb, w2t, h2);
    k_agg2f  <<<N_NODES / 4, 256, 0, stream>>>(rowptr, srcs, dinv, h2, b2, out);
}

// Round 6
// 285.337 us; speedup vs baseline: 3.8908x; 1.3192x over previous
//
#include <hip/hip_runtime.h>
#include <hip/hip_bf16.h>

#define N_NODES 50000
#define N_EDGES 800000
#define F_IN    128
#define F_HID   128
#define F_OUT   40
#define SCAN_BLOCKS ((N_NODES + 255) / 256)   // 196
#define N_TILES (N_NODES / 16)                // 3125 (exact)

typedef __attribute__((ext_vector_type(8))) short bf16x8;   // 8 bf16 = 4 VGPRs
typedef __attribute__((ext_vector_type(4))) float f32x4;

__device__ __forceinline__ float2 unpack_bf2(unsigned u) {
    float2 r;
    r.x = __uint_as_float(u << 16);
    r.y = __uint_as_float(u & 0xffff0000u);
    return r;
}
__device__ __forceinline__ unsigned pack_bf2(float x, float y) {
    union { unsigned u; __hip_bfloat16 h[2]; } cv;
    cv.h[0] = __float2bfloat16(x);
    cv.h[1] = __float2bfloat16(y);
    return cv.u;
}
__device__ __forceinline__ short bfraw(float v) {
    __hip_bfloat16 h = __float2bfloat16(v);
    return *(short*)&h;
}

// ---- 0. index-width sniff: int64 edge data has zero high words
__global__ void k_sniff(const unsigned int* __restrict__ w, int* __restrict__ flag) {
    __shared__ int nz;
    if (threadIdx.x == 0) nz = 0;
    __syncthreads();
    int local = 0;
    for (int i = threadIdx.x; i < 4096; i += 256)
        if (w[2 * i + 1] != 0u) local = 1;
    if (local) atomicOr(&nz, 1);
    __syncthreads();
    if (threadIdx.x == 0) flag[0] = (nz == 0) ? 1 : 0;
}

__device__ __forceinline__ int ld_src(const unsigned int* w, int is64, int e) {
    return is64 ? (int)w[2 * e] : (int)w[e];
}
__device__ __forceinline__ int ld_dst(const unsigned int* w, int is64, int e) {
    return is64 ? (int)w[2 * (N_EDGES + e)] : (int)w[N_EDGES + e];
}

// ---- 1. histogram of dst
__global__ void k_hist(const unsigned int* __restrict__ w, const int* __restrict__ flag,
                       int* __restrict__ deg) {
    int e = blockIdx.x * blockDim.x + threadIdx.x;
    if (e < N_EDGES) atomicAdd(&deg[ld_dst(w, flag[0], e)], 1);
}

// ---- 2a/2b/2c. exclusive scan -> rowptr, pos, dinv
__global__ void k_scan1(const int* __restrict__ deg, int* __restrict__ rowptr,
                        int* __restrict__ bsum) {
    __shared__ int sh[256];
    int tid = threadIdx.x;
    int i = blockIdx.x * 256 + tid;
    int v = (i < N_NODES) ? deg[i] : 0;
    sh[tid] = v;
    __syncthreads();
    for (int off = 1; off < 256; off <<= 1) {
        int t = (tid >= off) ? sh[tid - off] : 0;
        __syncthreads();
        sh[tid] += t;
        __syncthreads();
    }
    if (i < N_NODES) rowptr[i] = sh[tid] - v;
    if (tid == 255) bsum[blockIdx.x] = sh[255];
}
__global__ void k_scan2(int* __restrict__ bsum, int* __restrict__ boff) {
    __shared__ int sh[256];
    int tid = threadIdx.x;
    int v = (tid < SCAN_BLOCKS) ? bsum[tid] : 0;
    sh[tid] = v;
    __syncthreads();
    for (int off = 1; off < 256; off <<= 1) {
        int t = (tid >= off) ? sh[tid - off] : 0;
        __syncthreads();
        sh[tid] += t;
        __syncthreads();
    }
    if (tid < SCAN_BLOCKS) boff[tid] = sh[tid] - v;
}
__global__ void k_scan3(const int* __restrict__ deg, const int* __restrict__ boff,
                        int* __restrict__ rowptr, int* __restrict__ pos,
                        float* __restrict__ dinv) {
    int i = blockIdx.x * 256 + threadIdx.x;
    if (i >= N_NODES) return;
    int dg = deg[i];
    int rp = rowptr[i] + boff[blockIdx.x];
    rowptr[i] = rp;
    pos[i] = rp;
    dinv[i] = rsqrtf((float)dg + 1.0f);
    if (i == 0) rowptr[N_NODES] = N_EDGES;
}

// ---- 3. scatter (src, dinv[src]) into dst-sorted order
__global__ void k_scatter(const unsigned int* __restrict__ w, const int* __restrict__ flag,
                          const float* __restrict__ dinv,
                          int* __restrict__ pos, int2* __restrict__ srcw) {
    int e = blockIdx.x * blockDim.x + threadIdx.x;
    if (e >= N_EDGES) return;
    int is64 = flag[0];
    int s = ld_src(w, is64, e), d = ld_dst(w, is64, e);
    int slot = atomicAdd(&pos[d], 1);
    int2 rec;
    rec.x = s;
    rec.y = __float_as_int(dinv[s]);
    srcw[slot] = rec;
}

// ---- 4a. W1 [128][128] -> W1T bf16 [n][k]
__global__ void k_cvt_w1t(const float* __restrict__ W1, __hip_bfloat16* __restrict__ w1t) {
    int idx = blockIdx.x * blockDim.x + threadIdx.x;   // 16384
    int n = idx >> 7, k = idx & 127;
    w1t[idx] = __float2bfloat16(W1[k * F_HID + n]);
}

// ---- 4b. W2 [128][40] -> W2T bf16 [48][128], rows 40..47 zero
__global__ void k_cvt_w2t(const float* __restrict__ W2, __hip_bfloat16* __restrict__ w2t) {
    int idx = blockIdx.x * blockDim.x + threadIdx.x;   // 48*128 = 6144
    int n = idx >> 7, k = idx & 127;
    w2t[idx] = __float2bfloat16(n < F_OUT ? W2[k * F_OUT + n] : 0.f);
}

// ---- 5. h1 = x @ W1 via MFMA; x read fp32, converted in-register. h1 out bf16.
__global__ void k_gemm1m(const float* __restrict__ x,
                         const __hip_bfloat16* __restrict__ w1t,
                         __hip_bfloat16* __restrict__ h1b) {
    int wave = threadIdx.x >> 6, lane = threadIdx.x & 63;
    int tile = blockIdx.x * 4 + wave;
    if (tile >= N_TILES) return;
    int node0 = tile * 16;
    int m = lane & 15, q = lane >> 4;
    bf16x8 A[4];
    const float* arow = x + (size_t)(node0 + m) * F_IN + q * 8;
#pragma unroll
    for (int kt = 0; kt < 4; kt++) {
        float4 f0 = *(const float4*)(arow + kt * 32);
        float4 f1 = *(const float4*)(arow + kt * 32 + 4);
        bf16x8 a;
        a[0] = bfraw(f0.x); a[1] = bfraw(f0.y); a[2] = bfraw(f0.z); a[3] = bfraw(f0.w);
        a[4] = bfraw(f1.x); a[5] = bfraw(f1.y); a[6] = bfraw(f1.z); a[7] = bfraw(f1.w);
        A[kt] = a;
    }
#pragma unroll
    for (int c = 0; c < 8; c++) {
        f32x4 acc = {0.f, 0.f, 0.f, 0.f};
        const __hip_bfloat16* brow = w1t + (size_t)(c * 16 + m) * F_IN + q * 8;
#pragma unroll
        for (int kt = 0; kt < 4; kt++) {
            bf16x8 B = *(const bf16x8*)(brow + kt * 32);
            acc = __builtin_amdgcn_mfma_f32_16x16x32_bf16(A[kt], B, acc, 0, 0, 0);
        }
#pragma unroll
        for (int r = 0; r < 4; r++)
            h1b[(size_t)(node0 + q * 4 + r) * F_HID + c * 16 + m] = __float2bfloat16(acc[r]);
    }
}

// ---- 6. fused layer-1 aggregate + self-loop + bias + relu. One wave/node, unroll x4.
__global__ void k_agg1f(const int* __restrict__ rowptr, const int2* __restrict__ srcw,
                        const float* __restrict__ dinv, const __hip_bfloat16* __restrict__ h1b,
                        const float* __restrict__ b1, __hip_bfloat16* __restrict__ h1rb) {
    int wave = threadIdx.x >> 6, lane = threadIdx.x & 63;
    int node = blockIdx.x * 4 + wave;
    float di = dinv[node];
    int beg = rowptr[node], end = rowptr[node + 1];
    const unsigned* h1u = (const unsigned*)h1b;
    float2 acc = unpack_bf2(h1u[(size_t)node * 64 + lane]);
    float w0 = di * di;
    acc.x *= w0; acc.y *= w0;
    int e = beg;
    for (; e + 3 < end; e += 4) {
        int2 p0 = srcw[e], p1 = srcw[e + 1], p2 = srcw[e + 2], p3 = srcw[e + 3];
        unsigned u0 = h1u[(size_t)p0.x * 64 + lane];
        unsigned u1 = h1u[(size_t)p1.x * 64 + lane];
        unsigned u2 = h1u[(size_t)p2.x * 64 + lane];
        unsigned u3 = h1u[(size_t)p3.x * 64 + lane];
        float w0e = __int_as_float(p0.y) * di;
        float w1e = __int_as_float(p1.y) * di;
        float w2e = __int_as_float(p2.y) * di;
        float w3e = __int_as_float(p3.y) * di;
        float2 v0 = unpack_bf2(u0), v1 = unpack_bf2(u1), v2 = unpack_bf2(u2), v3 = unpack_bf2(u3);
        acc.x += v0.x * w0e + v1.x * w1e + v2.x * w2e + v3.x * w3e;
        acc.y += v0.y * w0e + v1.y * w1e + v2.y * w2e + v3.y * w3e;
    }
    for (; e < end; e++) {
        int2 p = srcw[e];
        float w = __int_as_float(p.y) * di;
        float2 v = unpack_bf2(h1u[(size_t)p.x * 64 + lane]);
        acc.x += v.x * w;
        acc.y += v.y * w;
    }
    float2 bb = ((const float2*)b1)[lane];
    acc.x = fmaxf(acc.x + bb.x, 0.f);
    acc.y = fmaxf(acc.y + bb.y, 0.f);
    ((unsigned*)h1rb)[(size_t)node * 64 + lane] = pack_bf2(acc.x, acc.y);
}

// ---- 7. h2 = h1r @ W2 via MFMA (N padded 40->48). h2 out fp32.
__global__ void k_gemm2m(const __hip_bfloat16* __restrict__ h1rb,
                         const __hip_bfloat16* __restrict__ w2t,
                         float* __restrict__ h2) {
    int wave = threadIdx.x >> 6, lane = threadIdx.x & 63;
    int tile = blockIdx.x * 4 + wave;
    if (tile >= N_TILES) return;
    int node0 = tile * 16;
    int m = lane & 15, q = lane >> 4;
    bf16x8 A[4];
    const __hip_bfloat16* arow = h1rb + (size_t)(node0 + m) * F_HID + q * 8;
#pragma unroll
    for (int kt = 0; kt < 4; kt++)
        A[kt] = *(const bf16x8*)(arow + kt * 32);
#pragma unroll
    for (int c = 0; c < 3; c++) {
        f32x4 acc = {0.f, 0.f, 0.f, 0.f};
        const __hip_bfloat16* brow = w2t + (size_t)(c * 16 + m) * F_HID + q * 8;
#pragma unroll
        for (int kt = 0; kt < 4; kt++) {
            bf16x8 B = *(const bf16x8*)(brow + kt * 32);
            acc = __builtin_amdgcn_mfma_f32_16x16x32_bf16(A[kt], B, acc, 0, 0, 0);
        }
        int col = c * 16 + m;
        if (col < F_OUT) {
#pragma unroll
            for (int r = 0; r < 4; r++)
                h2[(size_t)(node0 + q * 4 + r) * F_OUT + col] = acc[r];
        }
    }
}

// ---- 8. fused layer-2 aggregate + self-loop + bias + log_softmax. One wave/node, unroll x4.
__global__ void k_agg2f(const int* __restrict__ rowptr, const int2* __restrict__ srcw,
                        const float* __restrict__ dinv, const float* __restrict__ h2,
                        const float* __restrict__ b2, float* __restrict__ out) {
    int wave = threadIdx.x >> 6, lane = threadIdx.x & 63;
    int node = blockIdx.x * 4 + wave;
    float di = dinv[node];
    int beg = rowptr[node], end = rowptr[node + 1];
    int l = (lane < F_OUT) ? lane : 0;
    float acc = h2[(size_t)node * F_OUT + l] * di * di;
    int e = beg;
    for (; e + 3 < end; e += 4) {
        int2 p0 = srcw[e], p1 = srcw[e + 1], p2 = srcw[e + 2], p3 = srcw[e + 3];
        float v0 = h2[(size_t)p0.x * F_OUT + l];
        float v1 = h2[(size_t)p1.x * F_OUT + l];
        float v2 = h2[(size_t)p2.x * F_OUT + l];
        float v3 = h2[(size_t)p3.x * F_OUT + l];
        acc += v0 * (__int_as_float(p0.y) * di) + v1 * (__int_as_float(p1.y) * di)
             + v2 * (__int_as_float(p2.y) * di) + v3 * (__int_as_float(p3.y) * di);
    }
    for (; e < end; e++) {
        int2 p = srcw[e];
        acc += h2[(size_t)p.x * F_OUT + l] * (__int_as_float(p.y) * di);
    }
    float v = (lane < F_OUT) ? acc + b2[lane] : -INFINITY;
    float m = v;
    for (int off = 32; off; off >>= 1) m = fmaxf(m, __shfl_xor(m, off));
    float ex = (lane < F_OUT) ? __expf(v - m) : 0.f;
    float ssum = ex;
    for (int off = 32; off; off >>= 1) ssum += __shfl_xor(ssum, off);
    float ls = __logf(ssum);
    if (lane < F_OUT)
        out[(size_t)node * F_OUT + lane] = v - m - ls;
}

extern "C" void kernel_launch(void* const* d_in, const int* in_sizes, int n_in,
                              void* d_out, int out_size, void* d_ws, size_t ws_size,
                              hipStream_t stream) {
    const float* x  = (const float*)d_in[0];
    const float* W1 = (const float*)d_in[1];
    const float* b1 = (const float*)d_in[2];
    const float* W2 = (const float*)d_in[3];
    const float* b2 = (const float*)d_in[4];
    const unsigned int* ew = (const unsigned int*)d_in[5];
    float* out = (float*)d_out;

    // workspace (~42 MB)
    char* ws = (char*)d_ws;
    int*   flag   = (int*)ws;   ws += 256;
    int*   deg    = (int*)ws;   ws += ((N_NODES * 4 + 255) / 256) * 256;
    int*   pos    = deg;                                        // aliases deg
    float* dinv   = (float*)ws; ws += ((N_NODES * 4 + 255) / 256) * 256;
    int*   rowptr = (int*)ws;   ws += (((N_NODES + 1) * 4 + 255) / 256) * 256;
    int*   bsum   = (int*)ws;   ws += 1024;
    int*   boff   = (int*)ws;   ws += 1024;
    int2*  srcw   = (int2*)ws;  ws += (size_t)N_EDGES * 8;
    __hip_bfloat16* w1t  = (__hip_bfloat16*)ws; ws += F_IN * F_HID * 2;
    __hip_bfloat16* w2t  = (__hip_bfloat16*)ws; ws += 48 * F_HID * 2;
    __hip_bfloat16* h1b  = (__hip_bfloat16*)ws; ws += (size_t)N_NODES * F_HID * 2;
    __hip_bfloat16* h1rb = (__hip_bfloat16*)ws; ws += (size_t)N_NODES * F_HID * 2;
    float* h2 = (float*)ws;     ws += (size_t)N_NODES * F_OUT * 4;

    k_sniff<<<1, 256, 0, stream>>>(ew, flag);
    hipMemsetAsync(deg, 0, (size_t)N_NODES * 4, stream);
    k_hist   <<<(N_EDGES + 255) / 256, 256, 0, stream>>>(ew, flag, deg);
    k_scan1  <<<SCAN_BLOCKS, 256, 0, stream>>>(deg, rowptr, bsum);
    k_scan2  <<<1, 256, 0, stream>>>(bsum, boff);
    k_scan3  <<<SCAN_BLOCKS, 256, 0, stream>>>(deg, boff, rowptr, pos, dinv);
    k_scatter<<<(N_EDGES + 255) / 256, 256, 0, stream>>>(ew, flag, dinv, pos, srcw);

    k_cvt_w1t<<<(F_IN * F_HID) / 256, 256, 0, stream>>>(W1, w1t);
    k_cvt_w2t<<<(48 * F_HID) / 256, 256, 0, stream>>>(W2, w2t);

    k_gemm1m <<<(N_TILES + 3) / 4, 256, 0, stream>>>(x, w1t, h1b);
    k_agg1f  <<<N_NODES / 4, 256, 0, stream>>>(rowptr, srcw, dinv, h1b, b1, h1rb);
    k_gemm2m <<<(N_TILES + 3) / 4, 256, 0, stream>>>(h1rb, w2t, h2);
    k_agg2f  <<<N_NODES / 4, 256, 0, stream>>>(rowptr, srcw, dinv, h2, b2, out);
}